// Round 6
// baseline (34648.047 us; speedup 1.0000x reference)
//
#include <hip/hip_runtime.h>

#define NSTEP 515

// ---- workspace layout (bytes), all fp32 ----
#define OFF_WT1 0ull          // WT1[512][2048]  = Whh1^T                  (4 MB)
#define OFF_WT2 4194304ull    // WT2[1024][2048] = [Wih2;Whh2]^T           (8 MB)
#define OFF_WT3 12582912ull   // WT3[1024][2048] = [Wih3;Whh3]^T           (8 MB)
#define OFF_V1  20971520ull   // v1[2048]  = Wih1 @ W1[:,0]
#define OFF_U1  20979712ull   // u1[2048]  = Wih1 @ b1 + bih1 + bhh1
#define OFF_B2S 20987904ull   // b2s[2048] = bih2 + bhh2
#define OFF_B3S 20996096ull   // b3s[2048] = bih3 + bhh3
#define OFF_XT  21004288ull   // xT[512][128] f32                          (256 KB)
#define OFF_H   21266432ull   // H[3][2][128][512]  h ring                 (1.5 MB)
#define OFF_C   22839296ull   // C[3][128][512]     cell state             (768 KB)

__device__ __forceinline__ float sigm(float x) { return 1.0f / (1.0f + expf(-x)); }

// Sentinel: fills out with 0.75f. Real compute overwrites every element.
// Failure signatures: absmax~0.0508 -> nothing ran; ~0.75 -> lstm_step broken.
__global__ void fill_sentinel(float* __restrict__ out)
{
    int e = blockIdx.x * 256 + threadIdx.x;
    if (e < 65536) out[e] = 0.75f;
}

// Transpose one 2048x512 matrix into dst rows [koff .. koff+512).
__global__ void trans_w(const float* __restrict__ W, float* __restrict__ dst, int koff)
{
    int e = blockIdx.x * 256 + threadIdx.x;       // exactly 1,048,576
    int r = e >> 9, k = e & 511;
    dst[(size_t)(koff + k) * 2048 + r] = W[e];
}

// v1 = Wih1 @ W1[:,0]; u1 = Wih1 @ b1 + bih1 + bhh1; b2s/b3s = bih+bhh
__global__ void prep_vec(const float* __restrict__ Wih1, const float* __restrict__ W1,
                         const float* __restrict__ b1,
                         const float* __restrict__ bih1, const float* __restrict__ bhh1,
                         const float* __restrict__ bih2, const float* __restrict__ bhh2,
                         const float* __restrict__ bih3, const float* __restrict__ bhh3,
                         float* __restrict__ v1, float* __restrict__ u1,
                         float* __restrict__ b2s, float* __restrict__ b3s)
{
    int r = blockIdx.x * 256 + threadIdx.x;
    if (r >= 2048) return;
    float sv = 0.f, su = 0.f;
    for (int k = 0; k < 512; ++k) {
        float w = Wih1[r * 512 + k];
        sv += w * W1[k];
        su += w * b1[k];
    }
    v1[r] = sv;
    u1[r] = su + bih1[r] + bhh1[r];
    b2s[r] = bih2[r] + bhh2[r];
    b3s[r] = bih3[r] + bhh3[r];
}

__global__ void prep_xt(const float* __restrict__ x, float* __restrict__ xT)
{
    int e = blockIdx.x * 256 + threadIdx.x;
    if (e >= 65536) return;
    int b = e >> 9, t = e & 511;
    xT[t * 128 + b] = x[e];
}

__global__ void zero_state(char* __restrict__ ws)
{
    int e = blockIdx.x * 256 + threadIdx.x;       // covers 2304 KB in float4s
    float4 z = {0.f, 0.f, 0.f, 0.f};
    if (e < 147456) *(float4*)(ws + OFF_H + (size_t)e * 16) = z;   // H + C contiguous
}

// One skewed step: layer L computes t = w - L (if in range).
// All h reads hit ring slot prev=(w-1)&1, all writes go to slot cur=w&1.
// blocks 0..383: layer = blk>>7, 8 unit-groups x 16 batch-groups.
// block 384: output column out[:, w-3] from h3 (slot prev).
__global__ void lstm_step(char* __restrict__ ws, int w,
                          const float* __restrict__ W2, const float* __restrict__ b2,
                          float* __restrict__ out)
{
    const int cur = w & 1, prev = cur ^ 1;
    float* H = (float*)(ws + OFF_H);

    if (blockIdx.x == 384) {                       // output projection for t = w-3
        if (w < 3 || threadIdx.x >= 128) return;
        const int b = threadIdx.x;
        const float4* hp = (const float4*)(H + ((size_t)(4 + prev) * 128 + b) * 512);
        const float4* wp = (const float4*)W2;
        float acc = 0.f;
        for (int q = 0; q < 128; ++q) {
            float4 hv = hp[q], wv = wp[q];
            acc += hv.x * wv.x + hv.y * wv.y + hv.z * wv.z + hv.w * wv.w;
        }
        out[(size_t)b * 512 + (w - 3)] = acc + b2[0];
        return;
    }

    const int layer = blockIdx.x >> 7;
    const int t = w - layer;
    if (t < 0 || t >= 512) return;
    const int grp  = blockIdx.x & 127;
    const int ugrp = grp & 7;                      // 8 groups of 64 units
    const int bgrp = grp >> 3;                     // 16 groups of 8 batches
    const int nmat = (layer == 0) ? 1 : 2;

    __shared__ float hsh[2][8 * 512];              // 32 KB static
    for (int m = 0; m < nmat; ++m) {
        const int srcL = (layer == 0) ? 0 : ((m == 0) ? layer - 1 : layer);
        const float* src = H + ((size_t)(srcL * 2 + prev) * 128 + bgrp * 8) * 512;
        for (int i = threadIdx.x; i < 4096; i += 256) hsh[m][i] = src[i];
    }
    __syncthreads();

    const int u  = ugrp * 64 + (threadIdx.x & 63);
    const int bp = threadIdx.x >> 6;               // 0..3 -> batches bp*2, bp*2+1
    float acc[4][2] = {};
    const float* WT = (const float*)(ws + ((layer == 0) ? OFF_WT1
                                         : (layer == 1) ? OFF_WT2 : OFF_WT3));
    for (int m = 0; m < nmat; ++m) {
        const float* wt = WT + (size_t)m * 512 * 2048;
        const float* h0p = &hsh[m][(bp * 2 + 0) * 512];
        const float* h1p = &hsh[m][(bp * 2 + 1) * 512];
        for (int k = 0; k < 512; ++k) {
            const float h0 = h0p[k], h1 = h1p[k];
            const float* wrow = wt + (size_t)k * 2048 + u;
            #pragma unroll
            for (int g = 0; g < 4; ++g) {
                float wv = wrow[g * 512];
                acc[g][0] += wv * h0;
                acc[g][1] += wv * h1;
            }
        }
    }

    const float* v1  = (const float*)(ws + OFF_V1);
    const float* u1  = (const float*)(ws + OFF_U1);
    const float* bs  = (const float*)(ws + ((layer == 1) ? OFF_B2S : OFF_B3S));
    const float* xT  = (const float*)(ws + OFF_XT);
    float* C = (float*)(ws + OFF_C);
    #pragma unroll
    for (int e = 0; e < 2; ++e) {
        const int b = bgrp * 8 + bp * 2 + e;
        float gi = acc[0][e], gf = acc[1][e], gq = acc[2][e], go = acc[3][e];
        if (layer == 0) {
            const float xv = xT[t * 128 + b];
            gi += xv * v1[u]        + u1[u];
            gf += xv * v1[512 + u]  + u1[512 + u];
            gq += xv * v1[1024 + u] + u1[1024 + u];
            go += xv * v1[1536 + u] + u1[1536 + u];
        } else {
            gi += bs[u]; gf += bs[512 + u]; gq += bs[1024 + u]; go += bs[1536 + u];
        }
        const size_t ci = ((size_t)layer * 128 + b) * 512 + u;
        const float c = C[ci];
        const float cn = sigm(gf) * c + sigm(gi) * tanhf(gq);
        C[ci] = cn;
        H[((size_t)(layer * 2 + cur) * 128 + b) * 512 + u] = sigm(go) * tanhf(cn);
    }
}

// Kept to match the harness-provided template symbol (unused).
__global__ void Sequence_85564338471528_kernel() {}

extern "C" void kernel_launch(void* const* d_in, const int* in_sizes, int n_in,
                              void* d_out, int out_size, void* d_ws, size_t ws_size,
                              hipStream_t stream)
{
    const float* x    = (const float*)d_in[0];
    const float* W1   = (const float*)d_in[2];
    const float* b1   = (const float*)d_in[3];
    const float* W2   = (const float*)d_in[4];
    const float* b2   = (const float*)d_in[5];
    const float* Wih1 = (const float*)d_in[6];
    const float* Whh1 = (const float*)d_in[7];
    const float* bih1 = (const float*)d_in[8];
    const float* bhh1 = (const float*)d_in[9];
    const float* Wih2 = (const float*)d_in[10];
    const float* Whh2 = (const float*)d_in[11];
    const float* bih2 = (const float*)d_in[12];
    const float* bhh2 = (const float*)d_in[13];
    const float* Wih3 = (const float*)d_in[14];
    const float* Whh3 = (const float*)d_in[15];
    const float* bih3 = (const float*)d_in[16];
    const float* bhh3 = (const float*)d_in[17];
    char* ws = (char*)d_ws;
    float* out = (float*)d_out;

    fill_sentinel<<<256, 256, 0, stream>>>(out);

    trans_w<<<4096, 256, 0, stream>>>(Whh1, (float*)(ws + OFF_WT1), 0);
    trans_w<<<4096, 256, 0, stream>>>(Wih2, (float*)(ws + OFF_WT2), 0);
    trans_w<<<4096, 256, 0, stream>>>(Whh2, (float*)(ws + OFF_WT2), 512);
    trans_w<<<4096, 256, 0, stream>>>(Wih3, (float*)(ws + OFF_WT3), 0);
    trans_w<<<4096, 256, 0, stream>>>(Whh3, (float*)(ws + OFF_WT3), 512);
    prep_vec<<<8, 256, 0, stream>>>(Wih1, W1, b1, bih1, bhh1, bih2, bhh2, bih3, bhh3,
                                    (float*)(ws + OFF_V1), (float*)(ws + OFF_U1),
                                    (float*)(ws + OFF_B2S), (float*)(ws + OFF_B3S));
    prep_xt<<<256, 256, 0, stream>>>(x, (float*)(ws + OFF_XT));
    zero_state<<<576, 256, 0, stream>>>(ws);          // H ring + C = 0

    for (int w = 0; w < NSTEP; ++w)
        lstm_step<<<385, 256, 0, stream>>>(ws, w, W2, b2, out);
}

// Round 7
// 14302.321 us; speedup vs baseline: 2.4225x; 2.4225x over previous
//
#include <hip/hip_runtime.h>

typedef short short8 __attribute__((ext_vector_type(8)));
typedef float f32x4  __attribute__((ext_vector_type(4)));

#define NWG 96           // 32 wgs per layer, 16 units each
#define NSTEP 515

// ---- workspace layout (bytes) ----
#define OFF_WH1  0ull              // packed Whh1 frags: 32 ug * 64KB = 2MB
#define OFF_WH2  2097152ull        // packed Whh2
#define OFF_WH3  4194304ull        // packed Whh3
#define OFF_WI2  6291456ull        // packed Wih2 (streamed from per-XCD L2)
#define OFF_WI3  8388608ull        // packed Wih3
#define OFF_V1   10485760ull       // v1[2048] f32 (Wih1 @ W1)
#define OFF_U1   10493952ull       // u1[2048] f32 (Wih1 @ b1 + bih1 + bhh1)
#define OFF_B2   10502144ull       // bias2[2048] f32
#define OFF_B3   10510336ull       // bias3[2048] f32
#define OFF_XT   10518528ull       // xT[512][128] f32 (256KB)
#define OFF_HR   10780672ull       // h rings: [3 layer][2 slot][16 kb][8 mb][512] u16 = 768KB
#define OFF_P3   11567104ull       // part3: [2][32][128] f32 = 32KB
#define OFF_BAR  11599872ull       // global barrier counter

__device__ __forceinline__ unsigned short bf16rne(float f) {
    unsigned u = __float_as_uint(f);
    return (unsigned short)((u + 0x7FFFu + ((u >> 16) & 1u)) >> 16);
}

__device__ __forceinline__ float sigm(float x) { return 1.0f / (1.0f + expf(-x)); }

// Sentinel: 0.0508 absmax -> nothing ran; ~0.75 -> lstm_main broken; ~4e-4 -> PASS.
__global__ void fill_sentinel(float* __restrict__ out)
{
    int e = blockIdx.x * 256 + threadIdx.x;
    if (e < 65536) out[e] = 0.75f;
}

__global__ void zero_bar(char* __restrict__ ws)
{
    if (threadIdx.x < 16) ((unsigned*)(ws + OFF_BAR))[threadIdx.x] = 0u;
}

// Pack one 2048x512 gate matrix into MFMA B-fragments (bf16 bits).
// e = (((ug*4 + nb)*16 + kb)*64 + lane)*8 + j
// value = W[nb*512 + ug*16 + (lane&15)][kb*32 + (lane>>4)*8 + j]
__global__ void pack_w(const float* __restrict__ W, unsigned short* __restrict__ dst)
{
    int e = blockIdx.x * 256 + threadIdx.x;     // exactly 1,048,576
    int j    = e & 7;
    int lane = (e >> 3) & 63;
    int kb   = (e >> 9) & 15;
    int nb   = (e >> 13) & 3;
    int ug   = e >> 15;
    int row = nb * 512 + ug * 16 + (lane & 15);
    int col = kb * 32 + (lane >> 4) * 8 + j;
    dst[e] = bf16rne(W[row * 512 + col]);
}

// v1 = Wih1 @ W1[:,0]; u1 = Wih1 @ b1 + bih1 + bhh1; bias2/3 = bih+bhh
__global__ void prep_vec(const float* __restrict__ Wih1, const float* __restrict__ W1,
                         const float* __restrict__ b1,
                         const float* __restrict__ bih1, const float* __restrict__ bhh1,
                         const float* __restrict__ bih2, const float* __restrict__ bhh2,
                         const float* __restrict__ bih3, const float* __restrict__ bhh3,
                         float* __restrict__ v1, float* __restrict__ u1,
                         float* __restrict__ bias2, float* __restrict__ bias3)
{
    int r = blockIdx.x * 256 + threadIdx.x;
    if (r >= 2048) return;
    float sv = 0.f, su = 0.f;
    for (int k = 0; k < 512; ++k) {
        float w = Wih1[r * 512 + k];
        sv += w * W1[k];
        su += w * b1[k];
    }
    v1[r] = sv;
    u1[r] = su + bih1[r] + bhh1[r];
    bias2[r] = bih2[r] + bhh2[r];
    bias3[r] = bih3[r] + bhh3[r];
}

__global__ void prep_xt(const float* __restrict__ x, float* __restrict__ xT)
{
    int e = blockIdx.x * 256 + threadIdx.x;
    if (e >= 65536) return;
    int b = e >> 9, t = e & 511;
    xT[t * 128 + b] = x[e];
}

// Software global barrier: atomicAdd arrival (device-scope, m20), agent-scope
// acquire polling, __threadfence release/acquire. One arriver per block.
__device__ __forceinline__ void gbar(unsigned* bar, unsigned target)
{
    __syncthreads();
    if (threadIdx.x == 0) {
        __threadfence();                                   // release
        atomicAdd(bar, 1u);
        while (__hip_atomic_load(bar, __ATOMIC_ACQUIRE, __HIP_MEMORY_SCOPE_AGENT) < target) {}
        __threadfence();                                   // acquire
    }
    __syncthreads();
}

// Persistent wavefront-skewed 3-layer LSTM. 96 wgs x 256 thr, 64KB dynamic LDS.
// wg = layer*32 + ug; each wg owns 16 units (all 4 gates), all 128 batches.
// Skew: at step w, layer L computes t = w - L. All h reads hit ring slot prev,
// all writes go to slot cur -> one global barrier per step.
__global__ void __launch_bounds__(256)
lstm_main(char* __restrict__ ws, const float* __restrict__ W2,
          const float* __restrict__ b2, float* __restrict__ out)
{
    extern __shared__ char ldsraw[];
    unsigned short* w_lds = (unsigned short*)ldsraw;       // 32768 u16 = 64KB

    const int tid  = threadIdx.x;
    const int lane = tid & 63;
    const int wv   = tid >> 6;
    const int q    = lane >> 4;
    const int l15  = lane & 15;
    const int wg   = blockIdx.x;
    const int layer = wg >> 5;
    const int ug    = wg & 31;

    unsigned short* hr = (unsigned short*)(ws + OFF_HR);
    float* part3 = (float*)(ws + OFF_P3);
    const float* xT = (const float*)(ws + OFF_XT);
    unsigned* bar = (unsigned*)(ws + OFF_BAR);

    // park Whh B-fragments in LDS (64KB once)
    {
        const unsigned short* src = (const unsigned short*)
            (ws + ((layer == 0) ? OFF_WH1 : (layer == 1) ? OFF_WH2 : OFF_WH3))
            + (size_t)ug * 32768;
        for (int i = tid * 8; i < 32768; i += 256 * 8)
            *(short8*)(w_lds + i) = *(const short8*)(src + i);
    }
    // zero h rings: 768KB over 96 wgs = 8KB each
    {
        float4 z = {0.f, 0.f, 0.f, 0.f};
        char* hb = ws + OFF_HR + (size_t)wg * 8192;
        for (int i = tid * 16; i < 8192; i += 256 * 16) *(float4*)(hb + i) = z;
    }
    // per-lane constants: unit gu = ug*16 + l15, gate g
    float cv[4], cu_[4];
    {
        int gu = ug * 16 + l15;
        if (layer == 0) {
            const float* v1 = (const float*)(ws + OFF_V1);
            const float* u1 = (const float*)(ws + OFF_U1);
            #pragma unroll
            for (int g = 0; g < 4; ++g) { cv[g] = v1[g * 512 + gu]; cu_[g] = u1[g * 512 + gu]; }
        } else {
            const float* bs = (const float*)(ws + ((layer == 1) ? OFF_B2 : OFF_B3));
            #pragma unroll
            for (int g = 0; g < 4; ++g) { cv[g] = bs[g * 512 + gu]; cu_[g] = 0.f; }
        }
    }
    const float w2v = (layer == 2) ? W2[ug * 16 + l15] : 0.f;
    const float b2v = b2[0];
    const unsigned short* wi_g = (const unsigned short*)
        (ws + ((layer == 1) ? OFF_WI2 : OFF_WI3)) + (size_t)ug * 32768;

    float c_st[2][4] = {};          // cell state [m][rr], register-resident

    unsigned bstep = 0;
    gbar(bar, NWG * ++bstep);       // packed weights + zeroed rings visible

    for (int w = 0; w < NSTEP; ++w) {
        const int cur = w & 1, prev = cur ^ 1;
        const int t = w - layer;
        if (t >= 0 && t < 512) {
            f32x4 acc[2][4] = {};
            // mat 0 (L2/L3 only): Wih @ h_lower, B-frags streamed from global (L2-hit)
            if (layer != 0) {
                const unsigned short* hA = hr + (size_t)((layer - 1) * 2 + prev) * 65536;
                #pragma unroll
                for (int kb = 0; kb < 16; ++kb) {
                    short8 a0 = *(const short8*)(hA + ((kb * 8 + 2 * wv    ) * 512) + lane * 8);
                    short8 a1 = *(const short8*)(hA + ((kb * 8 + 2 * wv + 1) * 512) + lane * 8);
                    #pragma unroll
                    for (int nb = 0; nb < 4; ++nb) {
                        short8 bw = *(const short8*)(wi_g + ((nb * 16 + kb) * 512) + lane * 8);
                        acc[0][nb] = __builtin_amdgcn_mfma_f32_16x16x32_bf16(a0, bw, acc[0][nb], 0, 0, 0);
                        acc[1][nb] = __builtin_amdgcn_mfma_f32_16x16x32_bf16(a1, bw, acc[1][nb], 0, 0, 0);
                    }
                }
            }
            // mat 1: Whh @ h_self(t-1), B-frags from LDS
            {
                const unsigned short* hS = hr + (size_t)(layer * 2 + prev) * 65536;
                #pragma unroll
                for (int kb = 0; kb < 16; ++kb) {
                    short8 a0 = *(const short8*)(hS + ((kb * 8 + 2 * wv    ) * 512) + lane * 8);
                    short8 a1 = *(const short8*)(hS + ((kb * 8 + 2 * wv + 1) * 512) + lane * 8);
                    #pragma unroll
                    for (int nb = 0; nb < 4; ++nb) {
                        short8 bw = *(const short8*)(w_lds + ((nb * 16 + kb) * 512) + lane * 8);
                        acc[0][nb] = __builtin_amdgcn_mfma_f32_16x16x32_bf16(a0, bw, acc[0][nb], 0, 0, 0);
                        acc[1][nb] = __builtin_amdgcn_mfma_f32_16x16x32_bf16(a1, bw, acc[1][nb], 0, 0, 0);
                    }
                }
            }
            // epilogue: all 4 gates of unit gu=ug*16+l15 in-lane; batch = mblk*16+q*4+rr
            #pragma unroll
            for (int m = 0; m < 2; ++m) {
                const int mblk = 2 * wv + m;
                unsigned short* dblk = hr + (size_t)(layer * 2 + cur) * 65536
                                     + ((size_t)(ug >> 1) * 8 + mblk) * 512;
                #pragma unroll
                for (int rr = 0; rr < 4; ++rr) {
                    const int b = mblk * 16 + q * 4 + rr;
                    const float xv = (layer == 0) ? xT[t * 128 + b] : 1.0f;
                    float gi = acc[m][0][rr] + xv * cv[0] + cu_[0];
                    float gf = acc[m][1][rr] + xv * cv[1] + cu_[1];
                    float gg = acc[m][2][rr] + xv * cv[2] + cu_[2];
                    float go = acc[m][3][rr] + xv * cv[3] + cu_[3];
                    float c = sigm(gf) * c_st[m][rr] + sigm(gi) * tanhf(gg);
                    c_st[m][rr] = c;
                    float h = sigm(go) * tanhf(c);
                    // h-ring scatter: dest lane = ((ug&1)*2+(l15>>3))*16 + (q*4+rr), j = l15&7
                    dblk[(((ug & 1) * 2 + (l15 >> 3)) * 128) + (q * 4 + rr) * 8 + (l15 & 7)] = bf16rne(h);
                    if (layer == 2) {
                        float v = h * w2v;                  // partial of out[b][t]
                        v += __shfl_xor(v, 1); v += __shfl_xor(v, 2);
                        v += __shfl_xor(v, 4); v += __shfl_xor(v, 8);
                        if (l15 == 0)
                            part3[((size_t)cur * 32 + ug) * 128 + b] = v;
                    }
                }
            }
        }
        // final output for t = w-3 (32 ug-partials sealed at step w-1)
        if (layer == 2 && w >= 3) {
            const int b = (wg - 64) * 4 + wv;              // 32 wgs x 4 waves = 128
            float v = (lane < 32) ? part3[((size_t)prev * 32 + lane) * 128 + b] : 0.f;
            v += __shfl_xor(v, 1); v += __shfl_xor(v, 2); v += __shfl_xor(v, 4);
            v += __shfl_xor(v, 8); v += __shfl_xor(v, 16);
            if (lane == 0) out[(size_t)b * 512 + (w - 3)] = v + b2v;
        }
        gbar(bar, NWG * ++bstep);
    }
}

// Kept to match the harness-provided template symbol (unused).
__global__ void Sequence_85564338471528_kernel() {}

extern "C" void kernel_launch(void* const* d_in, const int* in_sizes, int n_in,
                              void* d_out, int out_size, void* d_ws, size_t ws_size,
                              hipStream_t stream)
{
    const float* x    = (const float*)d_in[0];
    const float* W1   = (const float*)d_in[2];
    const float* b1   = (const float*)d_in[3];
    const float* W2   = (const float*)d_in[4];
    const float* b2   = (const float*)d_in[5];
    const float* Wih1 = (const float*)d_in[6];
    const float* Whh1 = (const float*)d_in[7];
    const float* bih1 = (const float*)d_in[8];
    const float* bhh1 = (const float*)d_in[9];
    const float* Wih2 = (const float*)d_in[10];
    const float* Whh2 = (const float*)d_in[11];
    const float* bih2 = (const float*)d_in[12];
    const float* bhh2 = (const float*)d_in[13];
    const float* Wih3 = (const float*)d_in[14];
    const float* Whh3 = (const float*)d_in[15];
    const float* bih3 = (const float*)d_in[16];
    const float* bhh3 = (const float*)d_in[17];
    char* ws = (char*)d_ws;
    float* out = (float*)d_out;

    fill_sentinel<<<256, 256, 0, stream>>>(out);
    zero_bar<<<1, 64, 0, stream>>>(ws);

    pack_w<<<4096, 256, 0, stream>>>(Whh1, (unsigned short*)(ws + OFF_WH1));
    pack_w<<<4096, 256, 0, stream>>>(Whh2, (unsigned short*)(ws + OFF_WH2));
    pack_w<<<4096, 256, 0, stream>>>(Whh3, (unsigned short*)(ws + OFF_WH3));
    pack_w<<<4096, 256, 0, stream>>>(Wih2, (unsigned short*)(ws + OFF_WI2));
    pack_w<<<4096, 256, 0, stream>>>(Wih3, (unsigned short*)(ws + OFF_WI3));
    prep_vec<<<8, 256, 0, stream>>>(Wih1, W1, b1, bih1, bhh1, bih2, bhh2, bih3, bhh3,
                                    (float*)(ws + OFF_V1), (float*)(ws + OFF_U1),
                                    (float*)(ws + OFF_B2), (float*)(ws + OFF_B3));
    prep_xt<<<256, 256, 0, stream>>>(x, (float*)(ws + OFF_XT));

    lstm_main<<<dim3(NWG), dim3(256), 65536, stream>>>(ws, W2, b2, out);
}

// Round 8
// 12673.936 us; speedup vs baseline: 2.7338x; 1.1285x over previous
//
#include <hip/hip_runtime.h>

typedef short short8 __attribute__((ext_vector_type(8)));
typedef float f32x4  __attribute__((ext_vector_type(4)));

#define NWG 96           // 32 wgs per layer, 16 units each
#define NSTEP 515

// ---- workspace layout (bytes) ----
#define OFF_WH1  0ull              // packed Whh1 frags: 32 ug * 64KB = 2MB
#define OFF_WH2  2097152ull        // packed Whh2
#define OFF_WH3  4194304ull        // packed Whh3
#define OFF_WI2  6291456ull        // packed Wih2 (streamed from per-XCD L2)
#define OFF_WI3  8388608ull        // packed Wih3
#define OFF_V1   10485760ull       // v1[2048] f32 (Wih1 @ W1)
#define OFF_U1   10493952ull       // u1[2048] f32 (Wih1 @ b1 + bih1 + bhh1)
#define OFF_B2   10502144ull       // bias2[2048] f32
#define OFF_B3   10510336ull       // bias3[2048] f32
#define OFF_XT   10518528ull       // xT[512][128] f32 (256KB)
#define OFF_HR   10780672ull       // h rings: [3 layer][2 slot][16 kb][8 mb][512] u16 = 768KB
#define OFF_P3   11567104ull       // part3: [3 slot][32][128] f32 = 48KB (3-ring)
#define OFF_BAR  11616256ull       // global barrier counter

__device__ __forceinline__ unsigned short bf16rne(float f) {
    unsigned u = __float_as_uint(f);
    return (unsigned short)((u + 0x7FFFu + ((u >> 16) & 1u)) >> 16);
}

__device__ __forceinline__ float sigm(float x) { return 1.0f / (1.0f + expf(-x)); }

// Sentinel: 0.0508 absmax -> nothing ran; ~0.75 -> lstm_main broken; ~2e-4 -> PASS.
__global__ void fill_sentinel(float* __restrict__ out)
{
    int e = blockIdx.x * 256 + threadIdx.x;
    if (e < 65536) out[e] = 0.75f;
}

__global__ void zero_bar(char* __restrict__ ws)
{
    if (threadIdx.x < 16) ((unsigned*)(ws + OFF_BAR))[threadIdx.x] = 0u;
}

// Pack one 2048x512 gate matrix into MFMA B-fragments (bf16 bits).
// e = (((ug*4 + nb)*16 + kb)*64 + lane)*8 + j
// value = W[nb*512 + ug*16 + (lane&15)][kb*32 + (lane>>4)*8 + j]
__global__ void pack_w(const float* __restrict__ W, unsigned short* __restrict__ dst)
{
    int e = blockIdx.x * 256 + threadIdx.x;     // exactly 1,048,576
    int j    = e & 7;
    int lane = (e >> 3) & 63;
    int kb   = (e >> 9) & 15;
    int nb   = (e >> 13) & 3;
    int ug   = e >> 15;
    int row = nb * 512 + ug * 16 + (lane & 15);
    int col = kb * 32 + (lane >> 4) * 8 + j;
    dst[e] = bf16rne(W[row * 512 + col]);
}

// v1 = Wih1 @ W1[:,0]; u1 = Wih1 @ b1 + bih1 + bhh1; bias2/3 = bih+bhh
__global__ void prep_vec(const float* __restrict__ Wih1, const float* __restrict__ W1,
                         const float* __restrict__ b1,
                         const float* __restrict__ bih1, const float* __restrict__ bhh1,
                         const float* __restrict__ bih2, const float* __restrict__ bhh2,
                         const float* __restrict__ bih3, const float* __restrict__ bhh3,
                         float* __restrict__ v1, float* __restrict__ u1,
                         float* __restrict__ bias2, float* __restrict__ bias3)
{
    int r = blockIdx.x * 256 + threadIdx.x;
    if (r >= 2048) return;
    float sv = 0.f, su = 0.f;
    for (int k = 0; k < 512; ++k) {
        float w = Wih1[r * 512 + k];
        sv += w * W1[k];
        su += w * b1[k];
    }
    v1[r] = sv;
    u1[r] = su + bih1[r] + bhh1[r];
    bias2[r] = bih2[r] + bhh2[r];
    bias3[r] = bih3[r] + bhh3[r];
}

__global__ void prep_xt(const float* __restrict__ x, float* __restrict__ xT)
{
    int e = blockIdx.x * 256 + threadIdx.x;
    if (e >= 65536) return;
    int b = e >> 9, t = e & 511;
    xT[t * 128 + b] = x[e];
}

// Persistent wavefront-skewed 3-layer LSTM. 96 wgs x 256 thr, 64KB dynamic LDS.
// wg = layer*32 + ug; each wg owns 16 units (all 4 gates), all 128 batches.
// Split-phase software barrier per step: arrive (release) right after h store,
// out-reduction overlapped, then RELAXED poll + one acquire fence.
__global__ void __launch_bounds__(256)
lstm_main(char* __restrict__ ws, const float* __restrict__ W2,
          const float* __restrict__ b2, float* __restrict__ out)
{
    extern __shared__ char ldsraw[];
    unsigned short* w_lds = (unsigned short*)ldsraw;       // 32768 u16 = 64KB

    const int tid  = threadIdx.x;
    const int lane = tid & 63;
    const int wv   = tid >> 6;
    const int q    = lane >> 4;
    const int l15  = lane & 15;
    const int wg   = blockIdx.x;
    const int layer = wg >> 5;
    const int ug    = wg & 31;

    unsigned short* hr = (unsigned short*)(ws + OFF_HR);
    float* part3 = (float*)(ws + OFF_P3);
    const float* xT = (const float*)(ws + OFF_XT);
    unsigned* bar = (unsigned*)(ws + OFF_BAR);

    // park Whh B-fragments in LDS (64KB once)
    {
        const unsigned short* src = (const unsigned short*)
            (ws + ((layer == 0) ? OFF_WH1 : (layer == 1) ? OFF_WH2 : OFF_WH3))
            + (size_t)ug * 32768;
        for (int i = tid * 8; i < 32768; i += 256 * 8)
            *(short8*)(w_lds + i) = *(const short8*)(src + i);
    }
    // zero h rings: 768KB over 96 wgs = 8KB each
    {
        float4 z = {0.f, 0.f, 0.f, 0.f};
        char* hb = ws + OFF_HR + (size_t)wg * 8192;
        for (int i = tid * 16; i < 8192; i += 256 * 16) *(float4*)(hb + i) = z;
    }
    // per-lane constants: unit gu = ug*16 + l15, gate g
    float cv[4], cu_[4];
    {
        int gu = ug * 16 + l15;
        if (layer == 0) {
            const float* v1 = (const float*)(ws + OFF_V1);
            const float* u1 = (const float*)(ws + OFF_U1);
            #pragma unroll
            for (int g = 0; g < 4; ++g) { cv[g] = v1[g * 512 + gu]; cu_[g] = u1[g * 512 + gu]; }
        } else {
            const float* bs = (const float*)(ws + ((layer == 1) ? OFF_B2 : OFF_B3));
            #pragma unroll
            for (int g = 0; g < 4; ++g) { cv[g] = bs[g * 512 + gu]; cu_[g] = 0.f; }
        }
    }
    const float w2v = (layer == 2) ? W2[ug * 16 + l15] : 0.f;
    const float b2v = b2[0];
    const unsigned short* wi_g = (const unsigned short*)
        (ws + ((layer == 1) ? OFF_WI2 : OFF_WI3)) + (size_t)ug * 32768;

    float c_st[2][4] = {};          // cell state [m][rr], register-resident

    unsigned bstep = 0;
    // full barrier after init
    __syncthreads();
    if (tid == 0) {
        __threadfence();
        atomicAdd(bar, 1u);
        unsigned tgt = NWG * ++bstep;
        while (__hip_atomic_load(bar, __ATOMIC_RELAXED, __HIP_MEMORY_SCOPE_AGENT) < tgt)
            __builtin_amdgcn_s_sleep(1);
        __threadfence();
    }
    __syncthreads();

    for (int w = 0; w < NSTEP; ++w) {
        const int cur = w & 1, prev = cur ^ 1;
        const int t = w - layer;
        if (t >= 0 && t < 512) {
            f32x4 acc[2][4] = {};
            // mat 0 (L2/L3 only): Wih @ h_lower, B-frags streamed from global (L2-hit)
            if (layer != 0) {
                const unsigned short* hA = hr + (size_t)((layer - 1) * 2 + prev) * 65536;
                #pragma unroll
                for (int kb = 0; kb < 16; ++kb) {
                    short8 a0 = *(const short8*)(hA + ((kb * 8 + 2 * wv    ) * 512) + lane * 8);
                    short8 a1 = *(const short8*)(hA + ((kb * 8 + 2 * wv + 1) * 512) + lane * 8);
                    #pragma unroll
                    for (int nb = 0; nb < 4; ++nb) {
                        short8 bw = *(const short8*)(wi_g + ((nb * 16 + kb) * 512) + lane * 8);
                        acc[0][nb] = __builtin_amdgcn_mfma_f32_16x16x32_bf16(a0, bw, acc[0][nb], 0, 0, 0);
                        acc[1][nb] = __builtin_amdgcn_mfma_f32_16x16x32_bf16(a1, bw, acc[1][nb], 0, 0, 0);
                    }
                }
            }
            // mat 1: Whh @ h_self(t-1), B-frags from LDS
            {
                const unsigned short* hS = hr + (size_t)(layer * 2 + prev) * 65536;
                #pragma unroll
                for (int kb = 0; kb < 16; ++kb) {
                    short8 a0 = *(const short8*)(hS + ((kb * 8 + 2 * wv    ) * 512) + lane * 8);
                    short8 a1 = *(const short8*)(hS + ((kb * 8 + 2 * wv + 1) * 512) + lane * 8);
                    #pragma unroll
                    for (int nb = 0; nb < 4; ++nb) {
                        short8 bw = *(const short8*)(w_lds + ((nb * 16 + kb) * 512) + lane * 8);
                        acc[0][nb] = __builtin_amdgcn_mfma_f32_16x16x32_bf16(a0, bw, acc[0][nb], 0, 0, 0);
                        acc[1][nb] = __builtin_amdgcn_mfma_f32_16x16x32_bf16(a1, bw, acc[1][nb], 0, 0, 0);
                    }
                }
            }
            // epilogue: all 4 gates of unit gu=ug*16+l15 in-lane; batch = mblk*16+q*4+rr
            #pragma unroll
            for (int m = 0; m < 2; ++m) {
                const int mblk = 2 * wv + m;
                unsigned short* dblk = hr + (size_t)(layer * 2 + cur) * 65536
                                     + ((size_t)(ug >> 1) * 8 + mblk) * 512;
                #pragma unroll
                for (int rr = 0; rr < 4; ++rr) {
                    const int b = mblk * 16 + q * 4 + rr;
                    const float xv = (layer == 0) ? xT[t * 128 + b] : 1.0f;
                    float gi = acc[m][0][rr] + xv * cv[0] + cu_[0];
                    float gf = acc[m][1][rr] + xv * cv[1] + cu_[1];
                    float gg = acc[m][2][rr] + xv * cv[2] + cu_[2];
                    float go = acc[m][3][rr] + xv * cv[3] + cu_[3];
                    float c = sigm(gf) * c_st[m][rr] + sigm(gi) * tanhf(gg);
                    c_st[m][rr] = c;
                    float h = sigm(go) * tanhf(c);
                    // h-ring scatter: dest lane = ((ug&1)*2+(l15>>3))*16 + (q*4+rr), j = l15&7
                    dblk[(((ug & 1) * 2 + (l15 >> 3)) * 128) + (q * 4 + rr) * 8 + (l15 & 7)] = bf16rne(h);
                    if (layer == 2) {
                        float v = h * w2v;                  // partial of out[b][t]
                        v += __shfl_xor(v, 1); v += __shfl_xor(v, 2);
                        v += __shfl_xor(v, 4); v += __shfl_xor(v, 8);
                        if (l15 == 0)
                            part3[((size_t)(w % 3) * 32 + ug) * 128 + b] = v;
                    }
                }
            }
        }
        // ---- barrier arrive (release h-ring + part3 writes) ----
        __syncthreads();
        if (tid == 0) {
            __threadfence();
            atomicAdd(bar, 1u);
        }
        const unsigned tgt = NWG * ++bstep;
        // ---- overlapped: final output for t = w-3 (partials sealed at w-1, slot (w-1)%3) ----
        if (layer == 2 && w >= 3) {
            const int b = (wg - 64) * 4 + wv;              // 32 wgs x 4 waves = 128
            float v = (lane < 32) ? part3[((size_t)((w - 1) % 3) * 32 + lane) * 128 + b] : 0.f;
            v += __shfl_xor(v, 1); v += __shfl_xor(v, 2); v += __shfl_xor(v, 4);
            v += __shfl_xor(v, 8); v += __shfl_xor(v, 16);
            if (lane == 0) out[(size_t)b * 512 + (w - 3)] = v + b2v;
        }
        // ---- barrier wait (RELAXED poll, one acquire fence) ----
        if (tid == 0) {
            while (__hip_atomic_load(bar, __ATOMIC_RELAXED, __HIP_MEMORY_SCOPE_AGENT) < tgt)
                __builtin_amdgcn_s_sleep(1);
            __threadfence();
        }
        __syncthreads();
    }
}

// Kept to match the harness-provided template symbol (unused).
__global__ void Sequence_85564338471528_kernel() {}

extern "C" void kernel_launch(void* const* d_in, const int* in_sizes, int n_in,
                              void* d_out, int out_size, void* d_ws, size_t ws_size,
                              hipStream_t stream)
{
    const float* x    = (const float*)d_in[0];
    const float* W1   = (const float*)d_in[2];
    const float* b1   = (const float*)d_in[3];
    const float* W2   = (const float*)d_in[4];
    const float* b2   = (const float*)d_in[5];
    const float* Wih1 = (const float*)d_in[6];
    const float* Whh1 = (const float*)d_in[7];
    const float* bih1 = (const float*)d_in[8];
    const float* bhh1 = (const float*)d_in[9];
    const float* Wih2 = (const float*)d_in[10];
    const float* Whh2 = (const float*)d_in[11];
    const float* bih2 = (const float*)d_in[12];
    const float* bhh2 = (const float*)d_in[13];
    const float* Wih3 = (const float*)d_in[14];
    const float* Whh3 = (const float*)d_in[15];
    const float* bih3 = (const float*)d_in[16];
    const float* bhh3 = (const float*)d_in[17];
    char* ws = (char*)d_ws;
    float* out = (float*)d_out;

    fill_sentinel<<<256, 256, 0, stream>>>(out);
    zero_bar<<<1, 64, 0, stream>>>(ws);

    pack_w<<<4096, 256, 0, stream>>>(Whh1, (unsigned short*)(ws + OFF_WH1));
    pack_w<<<4096, 256, 0, stream>>>(Whh2, (unsigned short*)(ws + OFF_WH2));
    pack_w<<<4096, 256, 0, stream>>>(Whh3, (unsigned short*)(ws + OFF_WH3));
    pack_w<<<4096, 256, 0, stream>>>(Wih2, (unsigned short*)(ws + OFF_WI2));
    pack_w<<<4096, 256, 0, stream>>>(Wih3, (unsigned short*)(ws + OFF_WI3));
    prep_vec<<<8, 256, 0, stream>>>(Wih1, W1, b1, bih1, bhh1, bih2, bhh2, bih3, bhh3,
                                    (float*)(ws + OFF_V1), (float*)(ws + OFF_U1),
                                    (float*)(ws + OFF_B2), (float*)(ws + OFF_B3));
    prep_xt<<<256, 256, 0, stream>>>(x, (float*)(ws + OFF_XT));

    lstm_main<<<dim3(NWG), dim3(256), 65536, stream>>>(ws, W2, b2, out);
}

// Round 9
// 11352.987 us; speedup vs baseline: 3.0519x; 1.1164x over previous
//
#include <hip/hip_runtime.h>

typedef short short8 __attribute__((ext_vector_type(8)));
typedef float f32x4  __attribute__((ext_vector_type(4)));

#define NWG 96           // 32 wgs per layer, 16 units each
#define NSTEP 515
#define NGRP 8           // barrier groups
#define GSZ  12          // arrivers per group (96/8)

// ---- workspace layout (bytes) ----
#define OFF_WH1  0ull              // packed Whh1 frags: 32 ug * 64KB = 2MB
#define OFF_WH2  2097152ull        // packed Whh2
#define OFF_WH3  4194304ull        // packed Whh3
#define OFF_WI2  6291456ull        // packed Wih2 (streamed, L2-resident)
#define OFF_WI3  8388608ull        // packed Wih3
#define OFF_V1   10485760ull       // v1[2048] f32 (Wih1 @ W1)
#define OFF_U1   10493952ull       // u1[2048] f32 (Wih1 @ b1 + bih1 + bhh1)
#define OFF_B2   10502144ull       // bias2[2048] f32
#define OFF_B3   10510336ull       // bias3[2048] f32
#define OFF_XT   10518528ull       // xT[512][128] f32 (256KB)
#define OFF_HR   10780672ull       // h rings: [3 layer][2 slot][16 kb][8 mb][512] u16 = 768KB
#define OFF_P3   11567104ull       // part3: [3 slot][32][128] f32 = 48KB (3-ring)
#define OFF_BAR  11616256ull       // barrier block: root@0, flag@+128B, grp g@+256+g*128

__device__ __forceinline__ unsigned short bf16rne(float f) {
    unsigned u = __float_as_uint(f);
    return (unsigned short)((u + 0x7FFFu + ((u >> 16) & 1u)) >> 16);
}

__device__ __forceinline__ float sigm(float x) { return 1.0f / (1.0f + expf(-x)); }

// Sentinel: 0.0508 absmax -> nothing ran; ~0.75 -> lstm_main broken; ~2e-4 -> PASS.
__global__ void fill_sentinel(float* __restrict__ out)
{
    int e = blockIdx.x * 256 + threadIdx.x;
    if (e < 65536) out[e] = 0.75f;
}

__global__ void zero_bar(char* __restrict__ ws)
{
    int i = threadIdx.x;                         // 512 threads clear 2KB
    ((unsigned*)(ws + OFF_BAR))[i] = 0u;
}

// Pack one 2048x512 gate matrix into MFMA B-fragments (bf16 bits).
// e = (((ug*4 + nb)*16 + kb)*64 + lane)*8 + j
// value = W[nb*512 + ug*16 + (lane&15)][kb*32 + (lane>>4)*8 + j]
__global__ void pack_w(const float* __restrict__ W, unsigned short* __restrict__ dst)
{
    int e = blockIdx.x * 256 + threadIdx.x;     // exactly 1,048,576
    int j    = e & 7;
    int lane = (e >> 3) & 63;
    int kb   = (e >> 9) & 15;
    int nb   = (e >> 13) & 3;
    int ug   = e >> 15;
    int row = nb * 512 + ug * 16 + (lane & 15);
    int col = kb * 32 + (lane >> 4) * 8 + j;
    dst[e] = bf16rne(W[row * 512 + col]);
}

// v1 = Wih1 @ W1[:,0]; u1 = Wih1 @ b1 + bih1 + bhh1; bias2/3 = bih+bhh
__global__ void prep_vec(const float* __restrict__ Wih1, const float* __restrict__ W1,
                         const float* __restrict__ b1,
                         const float* __restrict__ bih1, const float* __restrict__ bhh1,
                         const float* __restrict__ bih2, const float* __restrict__ bhh2,
                         const float* __restrict__ bih3, const float* __restrict__ bhh3,
                         float* __restrict__ v1, float* __restrict__ u1,
                         float* __restrict__ bias2, float* __restrict__ bias3)
{
    int r = blockIdx.x * 256 + threadIdx.x;
    if (r >= 2048) return;
    float sv = 0.f, su = 0.f;
    for (int k = 0; k < 512; ++k) {
        float w = Wih1[r * 512 + k];
        sv += w * W1[k];
        su += w * b1[k];
    }
    v1[r] = sv;
    u1[r] = su + bih1[r] + bhh1[r];
    bias2[r] = bih2[r] + bhh2[r];
    bias3[r] = bih3[r] + bhh3[r];
}

__global__ void prep_xt(const float* __restrict__ x, float* __restrict__ xT)
{
    int e = blockIdx.x * 256 + threadIdx.x;
    if (e >= 65536) return;
    int b = e >> 9, t = e & 511;
    xT[t * 128 + b] = x[e];
}

// ---- hierarchical split-phase global barrier ----
// Arrive: release fence; group atomicAdd (12 contenders/line); group-finisher
// bumps root (8 contenders); root-finisher stores step into the flag line.
// Wait: poll flag only (no RMW/poll collision), one acquire fence.
__device__ __forceinline__ void gbar_arrive(unsigned* bar, int wg, unsigned s)
{
    __syncthreads();
    if (threadIdx.x == 0) {
        __threadfence();                                       // release (L2 wb)
        unsigned g = (unsigned)wg & 7u;
        unsigned old = atomicAdd(bar + 64 + g * 32, 1u);
        if (old == s * GSZ - 1) {
            unsigned ro = atomicAdd(bar, 1u);
            if (ro == s * NGRP - 1)
                __hip_atomic_store(bar + 32, s, __ATOMIC_RELAXED,
                                   __HIP_MEMORY_SCOPE_AGENT);
        }
    }
}
__device__ __forceinline__ void gbar_wait(unsigned* bar, unsigned s)
{
    if (threadIdx.x == 0) {
        while (__hip_atomic_load(bar + 32, __ATOMIC_RELAXED,
                                 __HIP_MEMORY_SCOPE_AGENT) < s)
            __builtin_amdgcn_s_sleep(1);
        __threadfence();                                       // acquire (inv)
    }
    __syncthreads();
}

// Persistent wavefront-skewed 3-layer LSTM. 96 wgs x 256 thr, 64KB dynamic LDS.
// wg = layer*32 + ug; each wg owns 16 units (all 4 gates), all 128 batches.
__global__ void __launch_bounds__(256)
lstm_main(char* __restrict__ ws, const float* __restrict__ W2,
          const float* __restrict__ b2, float* __restrict__ out)
{
    extern __shared__ char ldsraw[];
    unsigned short* w_lds = (unsigned short*)ldsraw;       // 32768 u16 = 64KB

    const int tid  = threadIdx.x;
    const int lane = tid & 63;
    const int wv   = tid >> 6;
    const int q    = lane >> 4;
    const int l15  = lane & 15;
    const int wg   = blockIdx.x;
    const int layer = wg >> 5;
    const int ug    = wg & 31;

    unsigned short* hr = (unsigned short*)(ws + OFF_HR);
    float* part3 = (float*)(ws + OFF_P3);
    const float* xT = (const float*)(ws + OFF_XT);
    unsigned* bar = (unsigned*)(ws + OFF_BAR);

    // park Whh B-fragments in LDS (64KB once)
    {
        const unsigned short* src = (const unsigned short*)
            (ws + ((layer == 0) ? OFF_WH1 : (layer == 1) ? OFF_WH2 : OFF_WH3))
            + (size_t)ug * 32768;
        for (int i = tid * 8; i < 32768; i += 256 * 8)
            *(short8*)(w_lds + i) = *(const short8*)(src + i);
    }
    // zero h rings: 768KB over 96 wgs = 8KB each
    {
        float4 z = {0.f, 0.f, 0.f, 0.f};
        char* hb = ws + OFF_HR + (size_t)wg * 8192;
        for (int i = tid * 16; i < 8192; i += 256 * 16) *(float4*)(hb + i) = z;
    }
    // per-lane constants: unit gu = ug*16 + l15, gate g
    float cv[4], cu_[4];
    {
        int gu = ug * 16 + l15;
        if (layer == 0) {
            const float* v1 = (const float*)(ws + OFF_V1);
            const float* u1 = (const float*)(ws + OFF_U1);
            #pragma unroll
            for (int g = 0; g < 4; ++g) { cv[g] = v1[g * 512 + gu]; cu_[g] = u1[g * 512 + gu]; }
        } else {
            const float* bs = (const float*)(ws + ((layer == 1) ? OFF_B2 : OFF_B3));
            #pragma unroll
            for (int g = 0; g < 4; ++g) { cv[g] = bs[g * 512 + gu]; cu_[g] = 0.f; }
        }
    }
    const float w2v = (layer == 2) ? W2[ug * 16 + l15] : 0.f;
    const float b2v = b2[0];
    const unsigned short* wi_g = (const unsigned short*)
        (ws + ((layer == 1) ? OFF_WI2 : OFF_WI3)) + (size_t)ug * 32768;

    float c_st[2][4] = {};          // cell state [m][rr], register-resident

    unsigned bstep = 1;
    gbar_arrive(bar, wg, bstep);    // init barrier: weights + zeroed rings
    gbar_wait(bar, bstep);

    for (int w = 0; w < NSTEP; ++w) {
        const int cur = w & 1, prev = cur ^ 1;
        const int t = w - layer;
        if (t >= 0 && t < 512) {
            f32x4 acc[2][4] = {};
            // mat 0 (L2/L3 only): Wih @ h_lower, B-frags streamed from global
            if (layer != 0) {
                const unsigned short* hA = hr + (size_t)((layer - 1) * 2 + prev) * 65536;
                #pragma unroll
                for (int kb = 0; kb < 16; ++kb) {
                    short8 a0 = *(const short8*)(hA + ((kb * 8 + 2 * wv    ) * 512) + lane * 8);
                    short8 a1 = *(const short8*)(hA + ((kb * 8 + 2 * wv + 1) * 512) + lane * 8);
                    #pragma unroll
                    for (int nb = 0; nb < 4; ++nb) {
                        short8 bw = *(const short8*)(wi_g + ((nb * 16 + kb) * 512) + lane * 8);
                        acc[0][nb] = __builtin_amdgcn_mfma_f32_16x16x32_bf16(a0, bw, acc[0][nb], 0, 0, 0);
                        acc[1][nb] = __builtin_amdgcn_mfma_f32_16x16x32_bf16(a1, bw, acc[1][nb], 0, 0, 0);
                    }
                }
            }
            // mat 1: Whh @ h_self(t-1), B-frags from LDS
            {
                const unsigned short* hS = hr + (size_t)(layer * 2 + prev) * 65536;
                #pragma unroll
                for (int kb = 0; kb < 16; ++kb) {
                    short8 a0 = *(const short8*)(hS + ((kb * 8 + 2 * wv    ) * 512) + lane * 8);
                    short8 a1 = *(const short8*)(hS + ((kb * 8 + 2 * wv + 1) * 512) + lane * 8);
                    #pragma unroll
                    for (int nb = 0; nb < 4; ++nb) {
                        short8 bw = *(const short8*)(w_lds + ((nb * 16 + kb) * 512) + lane * 8);
                        acc[0][nb] = __builtin_amdgcn_mfma_f32_16x16x32_bf16(a0, bw, acc[0][nb], 0, 0, 0);
                        acc[1][nb] = __builtin_amdgcn_mfma_f32_16x16x32_bf16(a1, bw, acc[1][nb], 0, 0, 0);
                    }
                }
            }
            // epilogue: all 4 gates of unit gu=ug*16+l15 in-lane; batch = mblk*16+q*4+rr
            #pragma unroll
            for (int m = 0; m < 2; ++m) {
                const int mblk = 2 * wv + m;
                unsigned short* dblk = hr + (size_t)(layer * 2 + cur) * 65536
                                     + ((size_t)(ug >> 1) * 8 + mblk) * 512;
                #pragma unroll
                for (int rr = 0; rr < 4; ++rr) {
                    const int b = mblk * 16 + q * 4 + rr;
                    const float xv = (layer == 0) ? xT[t * 128 + b] : 1.0f;
                    float gi = acc[m][0][rr] + xv * cv[0] + cu_[0];
                    float gf = acc[m][1][rr] + xv * cv[1] + cu_[1];
                    float gg = acc[m][2][rr] + xv * cv[2] + cu_[2];
                    float go = acc[m][3][rr] + xv * cv[3] + cu_[3];
                    float c = sigm(gf) * c_st[m][rr] + sigm(gi) * tanhf(gg);
                    c_st[m][rr] = c;
                    float h = sigm(go) * tanhf(c);
                    // h-ring scatter: dest lane = ((ug&1)*2+(l15>>3))*16 + (q*4+rr), j = l15&7
                    dblk[(((ug & 1) * 2 + (l15 >> 3)) * 128) + (q * 4 + rr) * 8 + (l15 & 7)] = bf16rne(h);
                    if (layer == 2) {
                        float v = h * w2v;                  // partial of out[b][t]
                        v += __shfl_xor(v, 1); v += __shfl_xor(v, 2);
                        v += __shfl_xor(v, 4); v += __shfl_xor(v, 8);
                        if (l15 == 0)
                            part3[((size_t)(w % 3) * 32 + ug) * 128 + b] = v;
                    }
                }
            }
        }
        // ---- barrier arrive (release h-ring + part3 writes) ----
        gbar_arrive(bar, wg, ++bstep);
        // ---- overlapped: final output for t = w-3 (partials sealed at w-1) ----
        if (layer == 2 && w >= 3) {
            const int b = (wg - 64) * 4 + wv;              // 32 wgs x 4 waves = 128
            float v = (lane < 32) ? part3[((size_t)((w - 1) % 3) * 32 + lane) * 128 + b] : 0.f;
            v += __shfl_xor(v, 1); v += __shfl_xor(v, 2); v += __shfl_xor(v, 4);
            v += __shfl_xor(v, 8); v += __shfl_xor(v, 16);
            if (lane == 0) out[(size_t)b * 512 + (w - 3)] = v + b2v;
        }
        // ---- barrier wait (poll flag line only, one acquire fence) ----
        gbar_wait(bar, bstep);
    }
}

// Kept to match the harness-provided template symbol (unused).
__global__ void Sequence_85564338471528_kernel() {}

extern "C" void kernel_launch(void* const* d_in, const int* in_sizes, int n_in,
                              void* d_out, int out_size, void* d_ws, size_t ws_size,
                              hipStream_t stream)
{
    const float* x    = (const float*)d_in[0];
    const float* W1   = (const float*)d_in[2];
    const float* b1   = (const float*)d_in[3];
    const float* W2   = (const float*)d_in[4];
    const float* b2   = (const float*)d_in[5];
    const float* Wih1 = (const float*)d_in[6];
    const float* Whh1 = (const float*)d_in[7];
    const float* bih1 = (const float*)d_in[8];
    const float* bhh1 = (const float*)d_in[9];
    const float* Wih2 = (const float*)d_in[10];
    const float* Whh2 = (const float*)d_in[11];
    const float* bih2 = (const float*)d_in[12];
    const float* bhh2 = (const float*)d_in[13];
    const float* Wih3 = (const float*)d_in[14];
    const float* Whh3 = (const float*)d_in[15];
    const float* bih3 = (const float*)d_in[16];
    const float* bhh3 = (const float*)d_in[17];
    char* ws = (char*)d_ws;
    float* out = (float*)d_out;

    fill_sentinel<<<256, 256, 0, stream>>>(out);
    zero_bar<<<1, 512, 0, stream>>>(ws);

    pack_w<<<4096, 256, 0, stream>>>(Whh1, (unsigned short*)(ws + OFF_WH1));
    pack_w<<<4096, 256, 0, stream>>>(Whh2, (unsigned short*)(ws + OFF_WH2));
    pack_w<<<4096, 256, 0, stream>>>(Whh3, (unsigned short*)(ws + OFF_WH3));
    pack_w<<<4096, 256, 0, stream>>>(Wih2, (unsigned short*)(ws + OFF_WI2));
    pack_w<<<4096, 256, 0, stream>>>(Wih3, (unsigned short*)(ws + OFF_WI3));
    prep_vec<<<8, 256, 0, stream>>>(Wih1, W1, b1, bih1, bhh1, bih2, bhh2, bih3, bhh3,
                                    (float*)(ws + OFF_V1), (float*)(ws + OFF_U1),
                                    (float*)(ws + OFF_B2), (float*)(ws + OFF_B3));
    prep_xt<<<256, 256, 0, stream>>>(x, (float*)(ws + OFF_XT));

    lstm_main<<<dim3(NWG), dim3(256), 65536, stream>>>(ws, W2, b2, out);
}

// Round 10
// 10491.522 us; speedup vs baseline: 3.3025x; 1.0821x over previous
//
#include <hip/hip_runtime.h>

typedef short short8 __attribute__((ext_vector_type(8)));
typedef float f32x4  __attribute__((ext_vector_type(4)));
typedef unsigned long long u64;

#define NWG 96           // 32 wgs per layer, 16 units each
#define NSTEP 515
#define NGRP 8           // barrier groups
#define GSZ  12          // arrivers per group (96/8)

// ---- workspace layout (bytes) ----
#define OFF_WH1  0ull              // packed Whh1 frags: 32 ug * 64KB = 2MB
#define OFF_WH2  2097152ull        // packed Whh2
#define OFF_WH3  4194304ull        // packed Whh3
#define OFF_WI2  6291456ull        // packed Wih2 (streamed, stays L2-hot now)
#define OFF_WI3  8388608ull        // packed Wih3
#define OFF_V1   10485760ull       // v1[2048] f32 (Wih1 @ W1)
#define OFF_U1   10493952ull       // u1[2048] f32 (Wih1 @ b1 + bih1 + bhh1)
#define OFF_B2   10502144ull       // bias2[2048] f32
#define OFF_B3   10510336ull       // bias3[2048] f32
#define OFF_XT   10518528ull       // xT[512][128] f32 (256KB)
#define OFF_HR   10780672ull       // h rings: [3 layer][2 slot][16 kb][8 mb][512] u16 = 768KB
#define OFF_P3   11567104ull       // part3: [3 slot][32][128] f32 = 48KB (3-ring)
#define OFF_BAR  11616256ull       // barrier: root@0, flag@+128B, grp g@+256+g*128

__device__ __forceinline__ unsigned short bf16rne(float f) {
    unsigned u = __float_as_uint(f);
    return (unsigned short)((u + 0x7FFFu + ((u >> 16) & 1u)) >> 16);
}

__device__ __forceinline__ float sigm(float x) { return 1.0f / (1.0f + expf(-x)); }

// Coherent (agent-scope, relaxed) 16B fragment load as 2x u64: bypasses stale
// L2 (sc bits), no cache-maintenance ops needed anywhere.
__device__ __forceinline__ short8 cload(const u64* p) {
    union { u64 d[2]; short8 s; } f;
    f.d[0] = __hip_atomic_load(p,     __ATOMIC_RELAXED, __HIP_MEMORY_SCOPE_AGENT);
    f.d[1] = __hip_atomic_load(p + 1, __ATOMIC_RELAXED, __HIP_MEMORY_SCOPE_AGENT);
    return f.s;
}

// Sentinel: 0.0508 absmax -> nothing ran; ~0.75 -> lstm_main broken; ~2e-4 -> PASS.
__global__ void fill_sentinel(float* __restrict__ out)
{
    int e = blockIdx.x * 256 + threadIdx.x;
    if (e < 65536) out[e] = 0.75f;
}

__global__ void zero_bar(char* __restrict__ ws)
{
    ((unsigned*)(ws + OFF_BAR))[threadIdx.x] = 0u;   // 512 thr clear 2KB
}

// Zero h rings + part3 in a PRE-kernel: kernel-boundary flush publishes the
// zeros coherently, so lstm_main needs no init barrier.
__global__ void zero_hr(char* __restrict__ ws)
{
    int e = blockIdx.x * 256 + threadIdx.x;
    float4 z = {0.f, 0.f, 0.f, 0.f};
    if (e < 52224) *(float4*)(ws + OFF_HR + (size_t)e * 16) = z;  // HR(768K)+P3(48K)
}

// Pack one 2048x512 gate matrix into MFMA B-fragments (bf16 bits).
__global__ void pack_w(const float* __restrict__ W, unsigned short* __restrict__ dst)
{
    int e = blockIdx.x * 256 + threadIdx.x;     // exactly 1,048,576
    int j    = e & 7;
    int lane = (e >> 3) & 63;
    int kb   = (e >> 9) & 15;
    int nb   = (e >> 13) & 3;
    int ug   = e >> 15;
    int row = nb * 512 + ug * 16 + (lane & 15);
    int col = kb * 32 + (lane >> 4) * 8 + j;
    dst[e] = bf16rne(W[row * 512 + col]);
}

// v1 = Wih1 @ W1[:,0]; u1 = Wih1 @ b1 + bih1 + bhh1; bias2/3 = bih+bhh
__global__ void prep_vec(const float* __restrict__ Wih1, const float* __restrict__ W1,
                         const float* __restrict__ b1,
                         const float* __restrict__ bih1, const float* __restrict__ bhh1,
                         const float* __restrict__ bih2, const float* __restrict__ bhh2,
                         const float* __restrict__ bih3, const float* __restrict__ bhh3,
                         float* __restrict__ v1, float* __restrict__ u1,
                         float* __restrict__ bias2, float* __restrict__ bias3)
{
    int r = blockIdx.x * 256 + threadIdx.x;
    if (r >= 2048) return;
    float sv = 0.f, su = 0.f;
    for (int k = 0; k < 512; ++k) {
        float w = Wih1[r * 512 + k];
        sv += w * W1[k];
        su += w * b1[k];
    }
    v1[r] = sv;
    u1[r] = su + bih1[r] + bhh1[r];
    bias2[r] = bih2[r] + bhh2[r];
    bias3[r] = bih3[r] + bhh3[r];
}

__global__ void prep_xt(const float* __restrict__ x, float* __restrict__ xT)
{
    int e = blockIdx.x * 256 + threadIdx.x;
    if (e >= 65536) return;
    int b = e >> 9, t = e & 511;
    xT[t * 128 + b] = x[e];
}

// ---- fence-free hierarchical split-phase barrier ----
// All shared data moves via agent-scope write-through atomics, so ordering is:
// atomic stores acked (vmcnt0 inside __syncthreads) -> arrival RMW -> tree ->
// flag store. Pollers read flag then data, both from the coherence point.
__device__ __forceinline__ void gbar_arrive(unsigned* bar, int wg, unsigned s)
{
    __syncthreads();                      // drains vmcnt: h stores are at L3
    if (threadIdx.x == 0) {
        unsigned g = (unsigned)wg & 7u;
        unsigned old = atomicAdd(bar + 64 + g * 32, 1u);
        if (old == s * GSZ - 1) {
            unsigned ro = atomicAdd(bar, 1u);
            if (ro == s * NGRP - 1)
                __hip_atomic_store(bar + 32, s, __ATOMIC_RELAXED,
                                   __HIP_MEMORY_SCOPE_AGENT);
        }
    }
}
__device__ __forceinline__ void gbar_wait(unsigned* bar, unsigned s)
{
    if (threadIdx.x == 0) {
        while (__hip_atomic_load(bar + 32, __ATOMIC_RELAXED,
                                 __HIP_MEMORY_SCOPE_AGENT) < s)
            __builtin_amdgcn_s_sleep(1);
    }
    __syncthreads();
}

// Persistent wavefront-skewed 3-layer LSTM. 96 wgs x 256 thr, 64KB dyn LDS.
// wg = layer*32 + ug; each wg owns 16 units (all 4 gates), all 128 batches.
__global__ void __launch_bounds__(256)
lstm_main(char* __restrict__ ws, const float* __restrict__ W2,
          const float* __restrict__ b2, float* __restrict__ out)
{
    extern __shared__ char ldsraw[];
    unsigned short* w_lds = (unsigned short*)ldsraw;       // 32768 u16 = 64KB
    __shared__ __align__(16) unsigned short stage[4][2][16][16];  // 4KB transpose stage

    const int tid  = threadIdx.x;
    const int lane = tid & 63;
    const int wv   = tid >> 6;
    const int q    = lane >> 4;
    const int l15  = lane & 15;
    const int wg   = blockIdx.x;
    const int layer = wg >> 5;
    const int ug    = wg & 31;

    unsigned short* hr = (unsigned short*)(ws + OFF_HR);
    float* part3 = (float*)(ws + OFF_P3);
    const float* xT = (const float*)(ws + OFF_XT);
    unsigned* bar = (unsigned*)(ws + OFF_BAR);

    // park Whh B-fragments in LDS (64KB once; plain cached loads, read-only)
    {
        const unsigned short* src = (const unsigned short*)
            (ws + ((layer == 0) ? OFF_WH1 : (layer == 1) ? OFF_WH2 : OFF_WH3))
            + (size_t)ug * 32768;
        for (int i = tid * 8; i < 32768; i += 256 * 8)
            *(short8*)(w_lds + i) = *(const short8*)(src + i);
    }
    // per-lane constants: unit gu = ug*16 + l15, gate g
    float cv[4], cu_[4];
    {
        int gu = ug * 16 + l15;
        if (layer == 0) {
            const float* v1 = (const float*)(ws + OFF_V1);
            const float* u1 = (const float*)(ws + OFF_U1);
            #pragma unroll
            for (int g = 0; g < 4; ++g) { cv[g] = v1[g * 512 + gu]; cu_[g] = u1[g * 512 + gu]; }
        } else {
            const float* bs = (const float*)(ws + ((layer == 1) ? OFF_B2 : OFF_B3));
            #pragma unroll
            for (int g = 0; g < 4; ++g) { cv[g] = bs[g * 512 + gu]; cu_[g] = 0.f; }
        }
    }
    const float w2v = (layer == 2) ? W2[ug * 16 + l15] : 0.f;
    const float b2v = b2[0];
    const unsigned short* wi_g = (const unsigned short*)
        (ws + ((layer == 1) ? OFF_WI2 : OFF_WI3)) + (size_t)ug * 32768;

    float c_st[2][4] = {};          // cell state [m][rr], register-resident
    __syncthreads();                // w_lds parked

    unsigned bstep = 0;
    for (int w = 0; w < NSTEP; ++w) {
        const int cur = w & 1, prev = cur ^ 1;
        const int t = w - layer;
        if (t >= 0 && t < 512) {
            f32x4 acc[2][4] = {};
            // mat 0 (L2/L3 layers): Wih @ h_lower; h via coherent loads
            if (layer != 0) {
                const u64* hA = (const u64*)(hr + (size_t)((layer - 1) * 2 + prev) * 65536);
                #pragma unroll
                for (int kb = 0; kb < 16; ++kb) {
                    short8 a0 = cload(hA + (kb * 8 + 2 * wv    ) * 128 + lane * 2);
                    short8 a1 = cload(hA + (kb * 8 + 2 * wv + 1) * 128 + lane * 2);
                    #pragma unroll
                    for (int nb = 0; nb < 4; ++nb) {
                        short8 bw = *(const short8*)(wi_g + ((nb * 16 + kb) * 512) + lane * 8);
                        acc[0][nb] = __builtin_amdgcn_mfma_f32_16x16x32_bf16(a0, bw, acc[0][nb], 0, 0, 0);
                        acc[1][nb] = __builtin_amdgcn_mfma_f32_16x16x32_bf16(a1, bw, acc[1][nb], 0, 0, 0);
                    }
                }
            }
            // mat 1: Whh @ h_self(t-1); B-frags from LDS
            {
                const u64* hS = (const u64*)(hr + (size_t)(layer * 2 + prev) * 65536);
                #pragma unroll
                for (int kb = 0; kb < 16; ++kb) {
                    short8 a0 = cload(hS + (kb * 8 + 2 * wv    ) * 128 + lane * 2);
                    short8 a1 = cload(hS + (kb * 8 + 2 * wv + 1) * 128 + lane * 2);
                    #pragma unroll
                    for (int nb = 0; nb < 4; ++nb) {
                        short8 bw = *(const short8*)(w_lds + ((nb * 16 + kb) * 512) + lane * 8);
                        acc[0][nb] = __builtin_amdgcn_mfma_f32_16x16x32_bf16(a0, bw, acc[0][nb], 0, 0, 0);
                        acc[1][nb] = __builtin_amdgcn_mfma_f32_16x16x32_bf16(a1, bw, acc[1][nb], 0, 0, 0);
                    }
                }
            }
            // epilogue: gates in-lane; h -> LDS transpose stage (+ part3 partials)
            #pragma unroll
            for (int m = 0; m < 2; ++m) {
                const int mblk = 2 * wv + m;
                #pragma unroll
                for (int rr = 0; rr < 4; ++rr) {
                    const int b = mblk * 16 + q * 4 + rr;
                    const float xv = (layer == 0) ? xT[t * 128 + b] : 1.0f;
                    float gi = acc[m][0][rr] + xv * cv[0] + cu_[0];
                    float gf = acc[m][1][rr] + xv * cv[1] + cu_[1];
                    float gg = acc[m][2][rr] + xv * cv[2] + cu_[2];
                    float go = acc[m][3][rr] + xv * cv[3] + cu_[3];
                    float c = sigm(gf) * c_st[m][rr] + sigm(gi) * tanhf(gg);
                    c_st[m][rr] = c;
                    float h = sigm(go) * tanhf(c);
                    stage[wv][m][q * 4 + rr][l15] = bf16rne(h);
                    if (layer == 2) {
                        float v = h * w2v;                  // partial of out[b][t]
                        v += __shfl_xor(v, 1); v += __shfl_xor(v, 2);
                        v += __shfl_xor(v, 4); v += __shfl_xor(v, 8);
                        if (l15 == 0)
                            __hip_atomic_store(&part3[((size_t)(w % 3) * 32 + ug) * 128 + b],
                                               v, __ATOMIC_RELAXED, __HIP_MEMORY_SCOPE_AGENT);
                    }
                }
            }
            // publish h: per-lane u64 chunks (write-through, agent-coherent)
            #pragma unroll
            for (int m = 0; m < 2; ++m) {
                const int mblk = 2 * wv + m;
                u64* dst64 = (u64*)(hr + (size_t)(layer * 2 + cur) * 65536
                                       + ((size_t)(ug >> 1) * 8 + mblk) * 512);
                const int row = lane >> 2, q4 = lane & 3;
                u64 v = *(const u64*)&stage[wv][m][row][q4 * 4];
                const int idx = (((ug & 1) * 2 + (q4 >> 1)) * 16 + row) * 2 + (q4 & 1);
                __hip_atomic_store(dst64 + idx, v, __ATOMIC_RELAXED,
                                   __HIP_MEMORY_SCOPE_AGENT);
            }
        }
        // ---- barrier arrive (syncthreads drains vmcnt -> stores visible) ----
        gbar_arrive(bar, wg, ++bstep);
        // ---- overlapped: final output for t = w-3 (partials sealed at w-1) ----
        if (layer == 2 && w >= 3) {
            const int b = (wg - 64) * 4 + wv;              // 32 wgs x 4 waves = 128
            float v = 0.f;
            if (lane < 32)
                v = __hip_atomic_load(&part3[((size_t)((w - 1) % 3) * 32 + lane) * 128 + b],
                                      __ATOMIC_RELAXED, __HIP_MEMORY_SCOPE_AGENT);
            v += __shfl_xor(v, 1); v += __shfl_xor(v, 2); v += __shfl_xor(v, 4);
            v += __shfl_xor(v, 8); v += __shfl_xor(v, 16);
            if (lane == 0) out[(size_t)b * 512 + (w - 3)] = v + b2v;
        }
        // ---- barrier wait (poll flag only; no fences anywhere) ----
        gbar_wait(bar, bstep);
    }
}

// Kept to match the harness-provided template symbol (unused).
__global__ void Sequence_85564338471528_kernel() {}

extern "C" void kernel_launch(void* const* d_in, const int* in_sizes, int n_in,
                              void* d_out, int out_size, void* d_ws, size_t ws_size,
                              hipStream_t stream)
{
    const float* x    = (const float*)d_in[0];
    const float* W1   = (const float*)d_in[2];
    const float* b1   = (const float*)d_in[3];
    const float* W2   = (const float*)d_in[4];
    const float* b2   = (const float*)d_in[5];
    const float* Wih1 = (const float*)d_in[6];
    const float* Whh1 = (const float*)d_in[7];
    const float* bih1 = (const float*)d_in[8];
    const float* bhh1 = (const float*)d_in[9];
    const float* Wih2 = (const float*)d_in[10];
    const float* Whh2 = (const float*)d_in[11];
    const float* bih2 = (const float*)d_in[12];
    const float* bhh2 = (const float*)d_in[13];
    const float* Wih3 = (const float*)d_in[14];
    const float* Whh3 = (const float*)d_in[15];
    const float* bih3 = (const float*)d_in[16];
    const float* bhh3 = (const float*)d_in[17];
    char* ws = (char*)d_ws;
    float* out = (float*)d_out;

    fill_sentinel<<<256, 256, 0, stream>>>(out);
    zero_bar<<<1, 512, 0, stream>>>(ws);
    zero_hr<<<204, 256, 0, stream>>>(ws);

    pack_w<<<4096, 256, 0, stream>>>(Whh1, (unsigned short*)(ws + OFF_WH1));
    pack_w<<<4096, 256, 0, stream>>>(Whh2, (unsigned short*)(ws + OFF_WH2));
    pack_w<<<4096, 256, 0, stream>>>(Whh3, (unsigned short*)(ws + OFF_WH3));
    pack_w<<<4096, 256, 0, stream>>>(Wih2, (unsigned short*)(ws + OFF_WI2));
    pack_w<<<4096, 256, 0, stream>>>(Wih3, (unsigned short*)(ws + OFF_WI3));
    prep_vec<<<8, 256, 0, stream>>>(Wih1, W1, b1, bih1, bhh1, bih2, bhh2, bih3, bhh3,
                                    (float*)(ws + OFF_V1), (float*)(ws + OFF_U1),
                                    (float*)(ws + OFF_B2), (float*)(ws + OFF_B3));
    prep_xt<<<256, 256, 0, stream>>>(x, (float*)(ws + OFF_XT));

    lstm_main<<<dim3(NWG), dim3(256), 65536, stream>>>(ws, W2, b2, out);
}